// Round 1
// baseline (1064.262 us; speedup 1.0000x reference)
//
#include <hip/hip_runtime.h>
#include <math.h>

#define TLEN 2048
#define EMB 1024
#define QKVDIM 3072
#define NROWS 4096   // TLEN * BSZ

// ---------------------------------------------------------------------------
// GEMM (NT): C[m][n] = sum_k A[m][k]*B[n][k] + bias[n]
// A: [M][K] row-major, B: [N][K] row-major. 128x128 tile, BK=16, 256 thr, 8x8/thread.
// LDS stored transposed (As[k][m]) so fragment reads are ds_read_b128.
// ---------------------------------------------------------------------------
__global__ __launch_bounds__(256, 2)
void gemm_nt_f32(const float* __restrict__ A, const float* __restrict__ B,
                 const float* __restrict__ bias, float* __restrict__ C,
                 int M, int N, int K)
{
    __shared__ float As[16][128];
    __shared__ float Bs[16][128];
    const int tid = threadIdx.x;
    const int tx = tid & 15, ty = tid >> 4;
    const int bm = blockIdx.y * 128, bn = blockIdx.x * 128;
    float acc[8][8] = {};
    for (int k0 = 0; k0 < K; k0 += 16) {
        #pragma unroll
        for (int u = 0; u < 2; ++u) {
            int idx = u * 256 + tid;          // 0..511
            int m   = idx >> 2;               // 0..127
            int kq  = (idx & 3) * 4;          // 0,4,8,12
            float4 va = *reinterpret_cast<const float4*>(&A[(size_t)(bm + m) * K + k0 + kq]);
            As[kq + 0][m] = va.x; As[kq + 1][m] = va.y; As[kq + 2][m] = va.z; As[kq + 3][m] = va.w;
            float4 vb = *reinterpret_cast<const float4*>(&B[(size_t)(bn + m) * K + k0 + kq]);
            Bs[kq + 0][m] = vb.x; Bs[kq + 1][m] = vb.y; Bs[kq + 2][m] = vb.z; Bs[kq + 3][m] = vb.w;
        }
        __syncthreads();
        #pragma unroll 4
        for (int kk = 0; kk < 16; ++kk) {
            float4 a0 = *reinterpret_cast<const float4*>(&As[kk][ty * 4]);
            float4 a1 = *reinterpret_cast<const float4*>(&As[kk][64 + ty * 4]);
            float4 b0 = *reinterpret_cast<const float4*>(&Bs[kk][tx * 4]);
            float4 b1 = *reinterpret_cast<const float4*>(&Bs[kk][64 + tx * 4]);
            const float a[8] = {a0.x, a0.y, a0.z, a0.w, a1.x, a1.y, a1.z, a1.w};
            const float b[8] = {b0.x, b0.y, b0.z, b0.w, b1.x, b1.y, b1.z, b1.w};
            #pragma unroll
            for (int i = 0; i < 8; ++i) {
                #pragma unroll
                for (int j = 0; j < 8; ++j)
                    acc[i][j] = fmaf(a[i], b[j], acc[i][j]);
            }
        }
        __syncthreads();
    }
    #pragma unroll
    for (int jh = 0; jh < 2; ++jh) {
        int n = bn + jh * 64 + tx * 4;
        float4 bv = *reinterpret_cast<const float4*>(&bias[n]);
        #pragma unroll
        for (int i = 0; i < 8; ++i) {
            int m = bm + ((i < 4) ? (ty * 4 + i) : (64 + ty * 4 + i - 4));
            float4 o;
            o.x = acc[i][jh * 4 + 0] + bv.x;
            o.y = acc[i][jh * 4 + 1] + bv.y;
            o.z = acc[i][jh * 4 + 2] + bv.z;
            o.w = acc[i][jh * 4 + 3] + bv.w;
            *reinterpret_cast<float4*>(&C[(size_t)m * N + n]) = o;
        }
    }
}

// ---------------------------------------------------------------------------
// Combined additive mask: cm[t][s] = (am[t][s]==0 ? 0 : am*-1e4) + (kpm[s][t]!=0 ? -inf : 0)
// kpm needs transposed access -> LDS tile transpose.
// ---------------------------------------------------------------------------
__global__ __launch_bounds__(256)
void build_cmask(const float* __restrict__ am, const int* __restrict__ kpm,
                 float* __restrict__ cm)
{
    __shared__ int kt[64][65];
    const int tid = threadIdx.x;
    const int s0 = blockIdx.x * 64, t0 = blockIdx.y * 64;
    #pragma unroll
    for (int u = 0; u < 4; ++u) {
        int idx = u * 256 + tid;
        int r  = idx >> 4;            // s-local
        int cq = (idx & 15) * 4;      // t-local
        int4 v = *reinterpret_cast<const int4*>(&kpm[(size_t)(s0 + r) * TLEN + t0 + cq]);
        kt[r][cq + 0] = v.x; kt[r][cq + 1] = v.y; kt[r][cq + 2] = v.z; kt[r][cq + 3] = v.w;
    }
    __syncthreads();
    #pragma unroll
    for (int u = 0; u < 4; ++u) {
        int idx = u * 256 + tid;
        int r  = idx >> 4;            // t-local
        int cq = (idx & 15) * 4;      // s-local
        float4 a = *reinterpret_cast<const float4*>(&am[(size_t)(t0 + r) * TLEN + s0 + cq]);
        const float av[4] = {a.x, a.y, a.z, a.w};
        float res[4];
        #pragma unroll
        for (int c = 0; c < 4; ++c) {
            float t = (av[c] == 0.0f) ? 0.0f : av[c] * -10000.0f;
            if (kt[cq + c][r] != 0) t = -INFINITY;  // kpm[s][t] != 0 -> masked
            res[c] = t;
        }
        float4 o = make_float4(res[0], res[1], res[2], res[3]);
        *reinterpret_cast<float4*>(&cm[(size_t)(t0 + r) * TLEN + s0 + cq]) = o;
    }
}

// ---------------------------------------------------------------------------
// Flash-style attention, fp32. Block = (t-tile 64) x (one bh). 256 threads, 4x4/thread.
// qkv row layout: qkv[(t*2+b)*3072 + h*192 + {0:q,64:k,128:v} + d]
// Output written into scrambled pre-projection layout:
//   X2[r][h*64+d], r = (t>=1024)*2048 + 2*(t&1023) + b   (the reference's reshape quirk)
// ---------------------------------------------------------------------------
__global__ __launch_bounds__(256, 2)
void attn_f32(const float* __restrict__ qkv, const float* __restrict__ cm,
              float* __restrict__ X2)
{
    __shared__ float Qt[64][68];   // [d][t]
    __shared__ float Kt[64][68];   // [d][s]
    __shared__ float Ps[64][68];   // [t][s]
    __shared__ float Vs[64][64];   // [s][d]
    const int tid = threadIdx.x;
    const int tx = tid & 15, ty = tid >> 4;
    const int bh = blockIdx.y;
    const int b = bh >> 4, h = bh & 15;
    const int t0 = blockIdx.x * 64;
    const float* qb = qkv + h * 192;
    const float* kb = qkv + h * 192 + 64;
    const float* vb = qkv + h * 192 + 128;

    #pragma unroll
    for (int u = 0; u < 4; ++u) {
        int idx = u * 256 + tid;
        int r  = idx >> 4;
        int dq = (idx & 15) * 4;
        float4 v = *reinterpret_cast<const float4*>(&qb[(size_t)((t0 + r) * 2 + b) * QKVDIM + dq]);
        Qt[dq + 0][r] = v.x; Qt[dq + 1][r] = v.y; Qt[dq + 2][r] = v.z; Qt[dq + 3][r] = v.w;
    }

    float O[4][4] = {};
    float m_run[4], l_run[4];
    #pragma unroll
    for (int i = 0; i < 4; ++i) { m_run[i] = -INFINITY; l_run[i] = 0.0f; }

    for (int s0 = 0; s0 < TLEN; s0 += 64) {
        #pragma unroll
        for (int u = 0; u < 4; ++u) {
            int idx = u * 256 + tid;
            int r  = idx >> 4;
            int dq = (idx & 15) * 4;
            size_t go = (size_t)((s0 + r) * 2 + b) * QKVDIM + dq;
            float4 kv = *reinterpret_cast<const float4*>(&kb[go]);
            Kt[dq + 0][r] = kv.x; Kt[dq + 1][r] = kv.y; Kt[dq + 2][r] = kv.z; Kt[dq + 3][r] = kv.w;
            float4 vv = *reinterpret_cast<const float4*>(&vb[go]);
            *reinterpret_cast<float4*>(&Vs[r][dq]) = vv;
        }
        __syncthreads();

        float s[4][4] = {};
        #pragma unroll 8
        for (int kk = 0; kk < 64; ++kk) {
            float4 a  = *reinterpret_cast<const float4*>(&Qt[kk][ty * 4]);
            float4 bq = *reinterpret_cast<const float4*>(&Kt[kk][tx * 4]);
            const float av[4] = {a.x, a.y, a.z, a.w};
            const float bv[4] = {bq.x, bq.y, bq.z, bq.w};
            #pragma unroll
            for (int i = 0; i < 4; ++i) {
                #pragma unroll
                for (int j = 0; j < 4; ++j)
                    s[i][j] = fmaf(av[i], bv[j], s[i][j]);
            }
        }

        float m_new[4], alpha[4], rs[4];
        #pragma unroll
        for (int i = 0; i < 4; ++i) {
            float4 cmv = *reinterpret_cast<const float4*>(
                &cm[(size_t)(t0 + ty * 4 + i) * TLEN + s0 + tx * 4]);
            const float cv[4] = {cmv.x, cmv.y, cmv.z, cmv.w};
            float tm = -INFINITY;
            #pragma unroll
            for (int j = 0; j < 4; ++j) {
                float v = 0.125f * s[i][j];
                v = (v == 0.0f) ? -INFINITY : v;   // reference quirk, pre-mask
                v += cv[j];
                s[i][j] = v;
                tm = fmaxf(tm, v);
            }
            #pragma unroll
            for (int off = 1; off < 16; off <<= 1)
                tm = fmaxf(tm, __shfl_xor(tm, off));
            m_new[i] = fmaxf(m_run[i], tm);
            alpha[i] = (m_run[i] > -INFINITY) ? __expf(m_run[i] - m_new[i]) : 0.0f;
            float ls = 0.0f;
            #pragma unroll
            for (int j = 0; j < 4; ++j) {
                float p = __expf(s[i][j] - m_new[i]);
                s[i][j] = p;
                ls += p;
            }
            #pragma unroll
            for (int off = 1; off < 16; off <<= 1)
                ls += __shfl_xor(ls, off);
            rs[i] = ls;
        }
        #pragma unroll
        for (int i = 0; i < 4; ++i) {
            m_run[i] = m_new[i];
            l_run[i] = l_run[i] * alpha[i] + rs[i];
            #pragma unroll
            for (int j = 0; j < 4; ++j) O[i][j] *= alpha[i];
            float4 pv = make_float4(s[i][0], s[i][1], s[i][2], s[i][3]);
            *reinterpret_cast<float4*>(&Ps[ty * 4 + i][tx * 4]) = pv;
        }
        __syncthreads();

        #pragma unroll 8
        for (int kk = 0; kk < 64; ++kk) {
            float4 vv = *reinterpret_cast<const float4*>(&Vs[kk][tx * 4]);
            const float vvv[4] = {vv.x, vv.y, vv.z, vv.w};
            float pa[4];
            #pragma unroll
            for (int i = 0; i < 4; ++i) pa[i] = Ps[ty * 4 + i][kk];
            #pragma unroll
            for (int i = 0; i < 4; ++i) {
                #pragma unroll
                for (int j = 0; j < 4; ++j)
                    O[i][j] = fmaf(pa[i], vvv[j], O[i][j]);
            }
        }
        __syncthreads();
    }

    #pragma unroll
    for (int i = 0; i < 4; ++i) {
        int t = t0 + ty * 4 + i;
        int r_out = ((t >= 1024) ? 2048 : 0) + 2 * (t & 1023) + b;
        float inv = 1.0f / l_run[i];
        float4 o = make_float4(O[i][0] * inv, O[i][1] * inv, O[i][2] * inv, O[i][3] * inv);
        *reinterpret_cast<float4*>(&X2[(size_t)r_out * EMB + h * 64 + tx * 4]) = o;
    }
}

// ---------------------------------------------------------------------------
extern "C" void kernel_launch(void* const* d_in, const int* in_sizes, int n_in,
                              void* d_out, int out_size, void* d_ws, size_t ws_size,
                              hipStream_t stream)
{
    const float* query = (const float*)d_in[0];
    // d_in[1] (key), d_in[2] (value) are ignored by the reference (self-attn from query)
    const float* am    = (const float*)d_in[3];
    const int*   kpm   = (const int*)d_in[4];
    const float* Wqkv  = (const float*)d_in[5];
    const float* bqkv  = (const float*)d_in[6];
    const float* Wout  = (const float*)d_in[7];
    const float* bout  = (const float*)d_in[8];
    float* out = (float*)d_out;

    char* ws = (char*)d_ws;
    float* qkv   = (float*)ws;                               // 4096*3072*4 = 50331648 B
    float* X2    = (float*)(ws + 50331648);                  // 4096*1024*4 = 16777216 B
    float* cmask = (float*)(ws + 50331648 + 16777216);       // 2048*2048*4 = 16777216 B

    build_cmask<<<dim3(32, 32), 256, 0, stream>>>(am, kpm, cmask);
    gemm_nt_f32<<<dim3(24, 32), 256, 0, stream>>>(query, Wqkv, bqkv, qkv, NROWS, QKVDIM, EMB);
    attn_f32<<<dim3(32, 32), 256, 0, stream>>>(qkv, cmask, X2);
    gemm_nt_f32<<<dim3(8, 32), 256, 0, stream>>>(X2, Wout, bout, out, NROWS, EMB, EMB);
}

// Round 2
// 299.788 us; speedup vs baseline: 3.5501x; 3.5501x over previous
//
#include <hip/hip_runtime.h>
#include <math.h>

#define TLEN 2048
#define EMB 1024
#define QKVD 3072
#define NROWS 4096

typedef unsigned short u16;
typedef unsigned int u32;
using frag_ab = __attribute__((ext_vector_type(8))) short;  // 8 bf16
using f32x4   = __attribute__((ext_vector_type(4))) float;

__device__ __forceinline__ u16 f2bf(float x) {
    u32 u = __builtin_bit_cast(u32, x);
    u = (u + 0x7FFFu + ((u >> 16) & 1u)) >> 16;
    return (u16)u;
}

#define GLL16(g, l) __builtin_amdgcn_global_load_lds(                         \
    (const __attribute__((address_space(1))) void*)(g),                       \
    (__attribute__((address_space(3))) void*)(l), 16, 0, 0)

// ---------------------------------------------------------------------------
// fp32 -> bf16 bulk convert (n multiple of 2048)
// ---------------------------------------------------------------------------
__global__ __launch_bounds__(256)
void cvt_bf16(const float* __restrict__ in, u16* __restrict__ out, int n)
{
    int i = (blockIdx.x * 256 + threadIdx.x) * 8;
    if (i >= n) return;
    float4 a = *reinterpret_cast<const float4*>(in + i);
    float4 b = *reinterpret_cast<const float4*>(in + i + 4);
    union { u16 h[8]; uint4 v; } o;
    o.h[0] = f2bf(a.x); o.h[1] = f2bf(a.y); o.h[2] = f2bf(a.z); o.h[3] = f2bf(a.w);
    o.h[4] = f2bf(b.x); o.h[5] = f2bf(b.y); o.h[6] = f2bf(b.z); o.h[7] = f2bf(b.w);
    *reinterpret_cast<uint4*>(out + i) = o.v;
}

// ---------------------------------------------------------------------------
// Combined additive mask: cm[t][s] = (am==0?0:am*-1e4) + (kpm[s][t]!=0 ? -inf : 0)
// ---------------------------------------------------------------------------
__global__ __launch_bounds__(256)
void build_cmask(const float* __restrict__ am, const int* __restrict__ kpm,
                 float* __restrict__ cm)
{
    __shared__ int kt[64][65];
    const int tid = threadIdx.x;
    const int s0 = blockIdx.x * 64, t0 = blockIdx.y * 64;
    #pragma unroll
    for (int u = 0; u < 4; ++u) {
        int idx = u * 256 + tid;
        int r  = idx >> 4;
        int cq = (idx & 15) * 4;
        int4 v = *reinterpret_cast<const int4*>(&kpm[(size_t)(s0 + r) * TLEN + t0 + cq]);
        kt[r][cq + 0] = v.x; kt[r][cq + 1] = v.y; kt[r][cq + 2] = v.z; kt[r][cq + 3] = v.w;
    }
    __syncthreads();
    #pragma unroll
    for (int u = 0; u < 4; ++u) {
        int idx = u * 256 + tid;
        int r  = idx >> 4;
        int cq = (idx & 15) * 4;
        float4 a = *reinterpret_cast<const float4*>(&am[(size_t)(t0 + r) * TLEN + s0 + cq]);
        const float av[4] = {a.x, a.y, a.z, a.w};
        float res[4];
        #pragma unroll
        for (int c = 0; c < 4; ++c) {
            float t = (av[c] == 0.0f) ? 0.0f : av[c] * -10000.0f;
            if (kt[cq + c][r] != 0) t = -INFINITY;
            res[c] = t;
        }
        *reinterpret_cast<float4*>(&cm[(size_t)(t0 + r) * TLEN + s0 + cq]) =
            make_float4(res[0], res[1], res[2], res[3]);
    }
}

// ---------------------------------------------------------------------------
// bf16 MFMA GEMM (NT): C[m][n] = sum_k A[m][k]*B[n][k] + bias[n]
// 128x128 tile, BK=32, 4 waves (2x2 of 64x64), 16x16x32 MFMA. m97 structure.
// ---------------------------------------------------------------------------
template <int OUT_BF16>
__global__ __launch_bounds__(256)
void gemm_nt_mfma(const u16* __restrict__ A, const u16* __restrict__ B,
                  const float* __restrict__ bias, void* __restrict__ Cp,
                  int M, int N, int K)
{
    __shared__ u16 As[128 * 32];
    __shared__ u16 Bs[128 * 32];
    const int tid  = threadIdx.x;
    const int lane = tid & 63;
    const int w    = tid >> 6;
    const int wr   = w >> 1, wc = w & 1;
    const int bm = blockIdx.y * 128, bn = blockIdx.x * 128;

    f32x4 acc[4][4];
    #pragma unroll
    for (int i = 0; i < 4; ++i)
        #pragma unroll
        for (int j = 0; j < 4; ++j)
            acc[i][j] = (f32x4){0.f, 0.f, 0.f, 0.f};

    const int srow = tid >> 2;            // 0..63
    const int skel = (tid & 3) * 8;       // k element offset
    const u16* Ag = A + (size_t)(bm + srow) * K + skel;
    const u16* Bg = B + (size_t)(bn + srow) * K + skel;
    u16* Asl = As + srow * 32 + skel;
    u16* Bsl = Bs + srow * 32 + skel;

    const int fr = lane & 15;             // frag row/col
    const int fk = (lane >> 4) * 8;       // k element within BK

    for (int k0 = 0; k0 < K; k0 += 32) {
        GLL16(Ag + k0, Asl);
        GLL16(Ag + (size_t)64 * K + k0, Asl + 64 * 32);
        GLL16(Bg + k0, Bsl);
        GLL16(Bg + (size_t)64 * K + k0, Bsl + 64 * 32);
        __syncthreads();
        frag_ab af[4], bfr[4];
        #pragma unroll
        for (int mf = 0; mf < 4; ++mf)
            af[mf] = *reinterpret_cast<const frag_ab*>(&As[(wr * 64 + mf * 16 + fr) * 32 + fk]);
        #pragma unroll
        for (int nf = 0; nf < 4; ++nf)
            bfr[nf] = *reinterpret_cast<const frag_ab*>(&Bs[(wc * 64 + nf * 16 + fr) * 32 + fk]);
        #pragma unroll
        for (int mf = 0; mf < 4; ++mf)
            #pragma unroll
            for (int nf = 0; nf < 4; ++nf)
                acc[mf][nf] = __builtin_amdgcn_mfma_f32_16x16x32_bf16(af[mf], bfr[nf], acc[mf][nf], 0, 0, 0);
        __syncthreads();
    }

    const int col0 = bn + wc * 64 + fr;
    const int row0 = bm + wr * 64 + (lane >> 4) * 4;
    #pragma unroll
    for (int nf = 0; nf < 4; ++nf) {
        const int col = col0 + nf * 16;
        const float bv = bias[col];
        #pragma unroll
        for (int mf = 0; mf < 4; ++mf) {
            #pragma unroll
            for (int i = 0; i < 4; ++i) {
                const size_t off = (size_t)(row0 + mf * 16 + i) * N + col;
                if (OUT_BF16) ((u16*)Cp)[off]  = f2bf(acc[mf][nf][i] + bv);
                else          ((float*)Cp)[off] = acc[mf][nf][i] + bv;
            }
        }
    }
}

// ---------------------------------------------------------------------------
// MFMA flash attention. Block: 64 t-rows x one (b,h). 4 waves x 16 rows.
// qkv bf16 layout: qkv[(t*2+b)*3072 + h*192 + {0:q,64:k,128:v} + d]
// Output X2 bf16 in the reference's scrambled pre-projection row order.
// ---------------------------------------------------------------------------
__global__ __launch_bounds__(256)
void attn_mfma(const u16* __restrict__ qkv, const float* __restrict__ cm,
               u16* __restrict__ X2)
{
    __shared__ u16 Qs[64 * 64];
    __shared__ u16 Ks[64 * 64];
    __shared__ u16 Vt[64 * 72];   // [d][s], padded stride 72 (144B, 16B aligned)
    __shared__ u16 Ps[64 * 72];   // [t][s]
    const int tid  = threadIdx.x;
    const int lane = tid & 63;
    const int w    = tid >> 6;
    const int bh = blockIdx.y;
    const int b = bh >> 4, h = bh & 15;
    const int t0 = blockIdx.x * 64;

    const u16* qbase = qkv + h * 192;
    const u16* kbase = qkv + h * 192 + 64;
    const u16* vbase = qkv + h * 192 + 128;

    const int srow = tid >> 3;           // 0..31 (row within 32-row staging round)
    const int sdel = (tid & 7) * 8;      // d element offset
    // stage Q once (async)
    #pragma unroll
    for (int u = 0; u < 2; ++u) {
        int r = u * 32 + srow;
        GLL16(qbase + (size_t)((t0 + r) * 2 + b) * QKVD + sdel, Qs + r * 64 + sdel);
    }

    const int fr = lane & 15;
    const int fg = lane >> 4;            // k-group / row-group
    const int fk = fg * 8;

    f32x4 oacc[4];
    #pragma unroll
    for (int nf = 0; nf < 4; ++nf) oacc[nf] = (f32x4){0.f, 0.f, 0.f, 0.f};
    float mrun[4], lrun[4];
    #pragma unroll
    for (int i = 0; i < 4; ++i) { mrun[i] = -INFINITY; lrun[i] = 0.f; }

    const int r0 = t0 + w * 16 + fg * 4;   // global t row for reg i=0

    for (int s0 = 0; s0 < TLEN; s0 += 64) {
        // stage K (async) + V (transposed, through regs)
        #pragma unroll
        for (int u = 0; u < 2; ++u) {
            int r = u * 32 + srow;
            GLL16(kbase + (size_t)((s0 + r) * 2 + b) * QKVD + sdel, Ks + r * 64 + sdel);
            uint4 raw = *reinterpret_cast<const uint4*>(
                vbase + (size_t)((s0 + r) * 2 + b) * QKVD + sdel);
            u32 rr[4] = {raw.x, raw.y, raw.z, raw.w};
            #pragma unroll
            for (int jj = 0; jj < 4; ++jj) {
                Vt[(sdel + 2 * jj + 0) * 72 + r] = (u16)(rr[jj] & 0xffffu);
                Vt[(sdel + 2 * jj + 1) * 72 + r] = (u16)(rr[jj] >> 16);
            }
        }
        __syncthreads();

        // ---- S = Q K^T (per wave: own 16 t-rows x 64 s) ----
        frag_ab aq[2];
        #pragma unroll
        for (int ks = 0; ks < 2; ++ks)
            aq[ks] = *reinterpret_cast<const frag_ab*>(&Qs[(w * 16 + fr) * 64 + ks * 32 + fk]);
        f32x4 sacc[4];
        #pragma unroll
        for (int nf = 0; nf < 4; ++nf) sacc[nf] = (f32x4){0.f, 0.f, 0.f, 0.f};
        #pragma unroll
        for (int nf = 0; nf < 4; ++nf)
            #pragma unroll
            for (int ks = 0; ks < 2; ++ks) {
                frag_ab bk = *reinterpret_cast<const frag_ab*>(
                    &Ks[(nf * 16 + fr) * 64 + ks * 32 + fk]);
                sacc[nf] = __builtin_amdgcn_mfma_f32_16x16x32_bf16(aq[ks], bk, sacc[nf], 0, 0, 0);
            }

        // ---- softmax (online), rows (l>>4)*4+i, cols fr within s-frag nf ----
        float tm[4] = {-INFINITY, -INFINITY, -INFINITY, -INFINITY};
        #pragma unroll
        for (int nf = 0; nf < 4; ++nf) {
            #pragma unroll
            for (int i = 0; i < 4; ++i) {
                float v = 0.125f * sacc[nf][i];
                v = (v == 0.0f) ? -INFINITY : v;           // reference quirk
                v += cm[(size_t)(r0 + i) * TLEN + s0 + nf * 16 + fr];
                sacc[nf][i] = v;
                tm[i] = fmaxf(tm[i], v);
            }
        }
        #pragma unroll
        for (int i = 0; i < 4; ++i) {
            #pragma unroll
            for (int off = 1; off < 16; off <<= 1)
                tm[i] = fmaxf(tm[i], __shfl_xor(tm[i], off));
        }
        float al[4], rs[4] = {0.f, 0.f, 0.f, 0.f};
        #pragma unroll
        for (int i = 0; i < 4; ++i) {
            float mn = fmaxf(mrun[i], tm[i]);
            al[i] = (mrun[i] > -INFINITY) ? __expf(mrun[i] - mn) : 0.f;
            mrun[i] = mn;
        }
        #pragma unroll
        for (int nf = 0; nf < 4; ++nf) {
            #pragma unroll
            for (int i = 0; i < 4; ++i) {
                float p = __expf(sacc[nf][i] - mrun[i]);
                sacc[nf][i] = p;
                rs[i] += p;
            }
        }
        #pragma unroll
        for (int i = 0; i < 4; ++i) {
            #pragma unroll
            for (int off = 1; off < 16; off <<= 1)
                rs[i] += __shfl_xor(rs[i], off);
            lrun[i] = lrun[i] * al[i] + rs[i];
            #pragma unroll
            for (int nf = 0; nf < 4; ++nf) oacc[nf][i] *= al[i];
        }
        // write P (bf16) to LDS, own wave's rows
        #pragma unroll
        for (int nf = 0; nf < 4; ++nf)
            #pragma unroll
            for (int i = 0; i < 4; ++i)
                Ps[(w * 16 + fg * 4 + i) * 72 + nf * 16 + fr] = f2bf(sacc[nf][i]);
        __syncthreads();

        // ---- O += P V ----
        frag_ab pa[2];
        #pragma unroll
        for (int ks = 0; ks < 2; ++ks)
            pa[ks] = *reinterpret_cast<const frag_ab*>(&Ps[(w * 16 + fr) * 72 + ks * 32 + fk]);
        #pragma unroll
        for (int nf = 0; nf < 4; ++nf)
            #pragma unroll
            for (int ks = 0; ks < 2; ++ks) {
                frag_ab bv = *reinterpret_cast<const frag_ab*>(
                    &Vt[(nf * 16 + fr) * 72 + ks * 32 + fk]);
                oacc[nf] = __builtin_amdgcn_mfma_f32_16x16x32_bf16(pa[ks], bv, oacc[nf], 0, 0, 0);
            }
        __syncthreads();
    }

    // epilogue: normalize + write scrambled rows
    #pragma unroll
    for (int i = 0; i < 4; ++i) {
        int t = r0 + i;
        int rout = ((t >= 1024) ? 2048 : 0) + 2 * (t & 1023) + b;
        float inv = 1.f / lrun[i];
        #pragma unroll
        for (int nf = 0; nf < 4; ++nf)
            X2[(size_t)rout * EMB + h * 64 + nf * 16 + fr] = f2bf(oacc[nf][i] * inv);
    }
}

// ---------------------------------------------------------------------------
extern "C" void kernel_launch(void* const* d_in, const int* in_sizes, int n_in,
                              void* d_out, int out_size, void* d_ws, size_t ws_size,
                              hipStream_t stream)
{
    const float* query = (const float*)d_in[0];
    const float* am    = (const float*)d_in[3];
    const int*   kpm   = (const int*)d_in[4];
    const float* Wqkv  = (const float*)d_in[5];
    const float* bqkv  = (const float*)d_in[6];
    const float* Wout  = (const float*)d_in[7];
    const float* bout  = (const float*)d_in[8];
    float* out = (float*)d_out;

    char* ws = (char*)d_ws;
    u16*   qkv_bf  = (u16*)(ws);                        // 4096*3072*2 = 25165824
    u16*   x2_bf   = (u16*)(ws + 25165824);             // 4096*1024*2 =  8388608
    float* cmask   = (float*)(ws + 33554432);           // 2048*2048*4 = 16777216
    u16*   q_bf    = (u16*)(ws + 50331648);             // 4096*1024*2 =  8388608
    u16*   wqkv_bf = (u16*)(ws + 58720256);             // 3072*1024*2 =  6291456
    u16*   wout_bf = (u16*)(ws + 65011712);             // 1024*1024*2 =  2097152

    cvt_bf16<<<2048, 256, 0, stream>>>(query, q_bf, 4194304);
    cvt_bf16<<<1536, 256, 0, stream>>>(Wqkv, wqkv_bf, 3145728);
    cvt_bf16<<<512,  256, 0, stream>>>(Wout, wout_bf, 1048576);
    build_cmask<<<dim3(32, 32), 256, 0, stream>>>(am, kpm, cmask);

    gemm_nt_mfma<1><<<dim3(24, 32), 256, 0, stream>>>(q_bf, wqkv_bf, bqkv, qkv_bf,
                                                      NROWS, QKVD, EMB);
    attn_mfma<<<dim3(32, 32), 256, 0, stream>>>(qkv_bf, cmask, x2_bf);
    gemm_nt_mfma<0><<<dim3(8, 32), 256, 0, stream>>>(x2_bf, wout_bf, bout, out,
                                                     NROWS, EMB, EMB);
}